// Round 15
// baseline (604.204 us; speedup 1.0000x reference)
//
#include <hip/hip_runtime.h>
#include <hip/hip_bf16.h>
#include <cstdint>
#include <cstddef>

typedef __bf16 bf16;
typedef __bf16 bf16x8 __attribute__((ext_vector_type(8)));
typedef float f32x4 __attribute__((ext_vector_type(4)));

#define N_PTS 131072
#define CDIM  512
#define C3    1536
#define HD    64
#define NH    8
#define KWIN  128

static __device__ __forceinline__ bf16 cvt(float x) { return (bf16)x; }

// async global->LDS, 16B per lane. LDS dest = wave-uniform base + lane*16.
static __device__ __forceinline__ void gld16(const bf16* g, bf16* l) {
    __builtin_amdgcn_global_load_lds(
        (const __attribute__((address_space(1))) void*)g,
        (__attribute__((address_space(3))) void*)l, 16, 0, 0);
}

// rotate a 128-bit value right by r 16-bit elements (r per-lane, 0..7):
// out elem k = in elem (k+r)&7. Branchless per-lane selects.
static __device__ __forceinline__ uint4 rot128(uint4 u, int r) {
    uint32_t x = u.x, y = u.y, z = u.z, w = u.w;
    uint32_t x1 = (x >> 16) | (y << 16), y1 = (y >> 16) | (z << 16),
             z1 = (z >> 16) | (w << 16), w1 = (w >> 16) | (x << 16);
    bool o1 = r & 1;
    x = o1 ? x1 : x; y = o1 ? y1 : y; z = o1 ? z1 : z; w = o1 ? w1 : w;
    bool o2 = r & 2;
    uint32_t t0 = x;
    x = o2 ? y : x; y = o2 ? z : y; z = o2 ? w : z; w = o2 ? t0 : w;
    bool o4 = r & 4;
    uint32_t tx = x, ty = y;
    x = o4 ? z : x; y = o4 ? w : y; z = o4 ? tx : z; w = o4 ? ty : w;
    uint4 o; o.x = x; o.y = y; o.z = z; o.w = w; return o;
}

// ---------------------------------------------------------------------------
// Weight prep: transpose + cast f32 -> bf16.  Wt[col][k] = W[k][col].
// ---------------------------------------------------------------------------
__global__ __launch_bounds__(256) void k_prep(
    const float* __restrict__ Wqkv, const float* __restrict__ Wproj,
    bf16* __restrict__ Wqkv_t, bf16* __restrict__ Wproj_t)
{
    int idx = blockIdx.x * 256 + threadIdx.x;
    if (idx < CDIM * C3) {
        int k = idx / C3, c = idx % C3;
        Wqkv_t[(size_t)c * CDIM + k] = cvt(Wqkv[idx]);
    } else {
        int j = idx - CDIM * C3;
        if (j < CDIM * CDIM) {
            int k = j / CDIM, c = j % CDIM;
            Wproj_t[(size_t)c * CDIM + k] = cvt(Wproj[j]);
        }
    }
}

// ---------------------------------------------------------------------------
// qkv GEMM with fused gather — FAT-WAVE variant:
// 128x256 block tile, 4 waves (2M x 2N), wave owns 64x128 (4x8 frags,
// acc = 128 regs). LDS reads per wave per K32: A4+B8 = 12 b128 per 32 MFMA
// (ratio 0.375 vs 0.5 for the 64x64 tile — 25% less LDS per FLOP).
// 256 thr, ~<=256 regs -> 2 waves/SIMD -> 2 INDEPENDENT blocks/CU.
// 2-deep LDS ring: (A 8KB + B 16KB) x 2 = 48 KB.
//
// A: reg-staged fused gather, depth-2 f32 pipeline (fp[2][4], parity static):
//    step-s top issues f32(s+3); step-s end packs s+2 (cvt->2x ds_write_b128).
//    pack(s+2)'s implicit wait retires f32(s+2) only (newer: B(s+1):4 +
//    f32(s+3):4 = vmcnt(8) -> B(s+1) stays in flight).
// B: gld16 with pre-swizzled global source (rotate-permute slots, verified
//    conflict-free R4-R14).
// vmcnt ledger at step-s wait: outstanding B(s+1):4 oldest, f32(s+3):4,
// B(s+2):4 -> vmcnt(8) retires exactly B(s+1); tails vmcnt(4) then (0).
// ---------------------------------------------------------------------------
template <int NT>
__global__ __launch_bounds__(256, 2) void k_qkv4(
    const float* __restrict__ feat, const bf16* __restrict__ Bt,
    const float* __restrict__ bias, const int* __restrict__ order,
    bf16* __restrict__ outp)
{
    __shared__ __align__(16) bf16 As[2][128 * 32];   // 8 KB each
    __shared__ __align__(16) bf16 Bs[2][256 * 32];   // 16 KB each
    __shared__ int ord_s[128];

    const int t    = threadIdx.x;
    const int lane = t & 63;
    const int wv   = t >> 6;          // 0..3
    const int wr   = wv >> 1;         // 0..1  (M half: 64 rows)
    const int wc   = wv & 1;          // 0..1  (N half: 128 cols)
    const int g    = lane >> 4, r16 = lane & 15;

    const int nwg = gridDim.x;
    const int bid = blockIdx.x;
    const int swz = (bid & 7) * (nwg >> 3) + (bid >> 3);  // grid %8==0
    const int m0  = (swz / NT) * 128;
    const int n0  = (swz % NT) * 256;

    const int NKT = CDIM / 32;   // 16

    if (t < 128) ord_s[t] = order[m0 + t];
    __syncthreads();

    // ---- A chunk ownership: chunks t (rows 0..63) and t+256 (rows 64..127).
    // chunk L: row=L>>2, phys slot p=L&3, src k-slot=(p-(row>>1))&3.
    const int rA0 = t >> 2;
    const int kA0 = ((t & 3) - (rA0 >> 1)) & 3;
    const int rA1 = (t + 256) >> 2;
    const int kA1 = ((t & 3) - (rA1 >> 1)) & 3;
    const float* gsrc0 = feat + (size_t)ord_s[rA0] * CDIM + kA0 * 8;
    const float* gsrc1 = feat + (size_t)ord_s[rA1] * CDIM + kA1 * 8;

    // ---- B staging: chunks t + q*256, q=0..3 (rows 0..255) ----
    const bf16* srcB[4];
#pragma unroll
    for (int q = 0; q < 4; ++q) {
        int L = t + q * 256;
        int row = L >> 2, s4 = ((L & 3) - (row >> 1)) & 3;
        srcB[q] = Bt + (size_t)(n0 + row) * CDIM + s4 * 8;
    }

    // ---- fragment read byte-offsets (rotate-permuted slots) ----
    int aoff[4], boff[8];
#pragma unroll
    for (int m = 0; m < 4; ++m) {
        int row = wr * 64 + m * 16 + r16;
        aoff[m] = row * 64 + (((g + (row >> 1)) & 3) << 4);
    }
#pragma unroll
    for (int n = 0; n < 8; ++n) {
        int row = wc * 128 + n * 16 + r16;
        boff[n] = row * 64 + (((g + (row >> 1)) & 3) << 4);
    }

    f32x4 acc[4][8];
    const f32x4 z = {0.f, 0.f, 0.f, 0.f};
#pragma unroll
    for (int m = 0; m < 4; ++m)
#pragma unroll
        for (int n = 0; n < 8; ++n) acc[m][n] = z;

    auto stageB = [&](int s) {
        const int b = s & 1;
#pragma unroll
        for (int q = 0; q < 4; ++q)
            gld16(srcB[q] + s * 32, &Bs[b][(size_t)(q * 256 + wv * 64) * 8]);
    };
    auto packA2 = [&](int s, float4 a0, float4 a1, float4 b0, float4 b1) {
        union { bf16 e[8]; uint4 u; } p0, p1;
        p0.e[0] = cvt(a0.x); p0.e[1] = cvt(a0.y); p0.e[2] = cvt(a0.z); p0.e[3] = cvt(a0.w);
        p0.e[4] = cvt(a1.x); p0.e[5] = cvt(a1.y); p0.e[6] = cvt(a1.z); p0.e[7] = cvt(a1.w);
        p1.e[0] = cvt(b0.x); p1.e[1] = cvt(b0.y); p1.e[2] = cvt(b0.z); p1.e[3] = cvt(b0.w);
        p1.e[4] = cvt(b1.x); p1.e[5] = cvt(b1.y); p1.e[6] = cvt(b1.z); p1.e[7] = cvt(b1.w);
        char* ab = reinterpret_cast<char*>(&As[s & 1][0]);
        *reinterpret_cast<uint4*>(ab + t * 16)         = p0.u;
        *reinterpret_cast<uint4*>(ab + (t + 256) * 16) = p1.u;
    };
    auto compute = [&](int s) {
        const int b = s & 1;
        const char* ab = reinterpret_cast<const char*>(&As[b][0]);
        const char* bb = reinterpret_cast<const char*>(&Bs[b][0]);
        bf16x8 af[4], bv[8];
#pragma unroll
        for (int m = 0; m < 4; ++m)
            af[m] = *reinterpret_cast<const bf16x8*>(ab + aoff[m]);
#pragma unroll
        for (int n = 0; n < 8; ++n)
            bv[n] = *reinterpret_cast<const bf16x8*>(bb + boff[n]);
        __builtin_amdgcn_s_setprio(1);
#pragma unroll
        for (int m = 0; m < 4; ++m)
#pragma unroll
            for (int n = 0; n < 8; ++n)
                acc[m][n] = __builtin_amdgcn_mfma_f32_16x16x32_bf16(
                    af[m], bv[n], acc[m][n], 0, 0, 0);
        __builtin_amdgcn_s_setprio(0);
    };

    float4 fp[2][4];   // depth-2 gather pipeline (parity-indexed, static)

    // ---------------- prologue ----------------
    {
        float4 t00 = *reinterpret_cast<const float4*>(gsrc0);
        float4 t01 = *reinterpret_cast<const float4*>(gsrc0 + 4);
        float4 t02 = *reinterpret_cast<const float4*>(gsrc1);
        float4 t03 = *reinterpret_cast<const float4*>(gsrc1 + 4);
        float4 t10 = *reinterpret_cast<const float4*>(gsrc0 + 32);
        float4 t11 = *reinterpret_cast<const float4*>(gsrc0 + 36);
        float4 t12 = *reinterpret_cast<const float4*>(gsrc1 + 32);
        float4 t13 = *reinterpret_cast<const float4*>(gsrc1 + 36);
        stageB(0); stageB(1);
        packA2(0, t00, t01, t02, t03);
        packA2(1, t10, t11, t12, t13);
        fp[0][0] = *reinterpret_cast<const float4*>(gsrc0 + 64);
        fp[0][1] = *reinterpret_cast<const float4*>(gsrc0 + 68);
        fp[0][2] = *reinterpret_cast<const float4*>(gsrc1 + 64);
        fp[0][3] = *reinterpret_cast<const float4*>(gsrc1 + 68);
        // outstanding: B(0):4 oldest, B(1):4, f32(2):4 -> retire B(0)
        asm volatile("s_waitcnt vmcnt(8) lgkmcnt(0)" ::: "memory");
        __builtin_amdgcn_s_barrier();
    }

    // ---------------- main loop ----------------
#pragma unroll
    for (int s = 0; s < NKT; ++s) {
        if (s + 3 < NKT) {
            const float* p0 = gsrc0 + (size_t)(s + 3) * 32;
            const float* p1 = gsrc1 + (size_t)(s + 3) * 32;
            fp[(s + 1) & 1][0] = *reinterpret_cast<const float4*>(p0);
            fp[(s + 1) & 1][1] = *reinterpret_cast<const float4*>(p0 + 4);
            fp[(s + 1) & 1][2] = *reinterpret_cast<const float4*>(p1);
            fp[(s + 1) & 1][3] = *reinterpret_cast<const float4*>(p1 + 4);
        }
        compute(s);
        if (s == NKT - 1) break;
        asm volatile("s_waitcnt lgkmcnt(0)" ::: "memory");
        __builtin_amdgcn_s_barrier();           // all waves done reading buf[s&1]
        if (s + 2 < NKT) {
            packA2(s + 2, fp[s & 1][0], fp[s & 1][1], fp[s & 1][2], fp[s & 1][3]);
            stageB(s + 2);
            asm volatile("s_waitcnt lgkmcnt(0)" ::: "memory");
            if (s + 3 < NKT)
                asm volatile("s_waitcnt vmcnt(8)" ::: "memory");
            else
                asm volatile("s_waitcnt vmcnt(4)" ::: "memory");
        } else {
            asm volatile("s_waitcnt vmcnt(0)" ::: "memory");
        }
        __builtin_amdgcn_s_barrier();
    }

    // ---------------- epilogue: D layout col=lane&15, row=(lane>>4)*4+j ----
    const int ldo = NT * 256;
#pragma unroll
    for (int n = 0; n < 8; ++n) {
        int col = n0 + wc * 128 + n * 16 + r16;
        float b = bias[col];
#pragma unroll
        for (int m = 0; m < 4; ++m)
#pragma unroll
            for (int j = 0; j < 4; ++j) {
                int row = m0 + wr * 64 + m * 16 + g * 4 + j;
                outp[(size_t)row * ldo + col] = cvt(acc[m][n][j] + b);
            }
    }
}

// ---------------------------------------------------------------------------
// proj GEMM — R8/R14 structure verbatim (proven): 128x256 tile, BK=32,
// 8 waves, 2-deep ring, rotate-permute LDS, gld16 both operands, vmcnt(3).
// ---------------------------------------------------------------------------
template <int NT>
__global__ __launch_bounds__(512, 4) void k_proj(
    const bf16* __restrict__ Ag, const bf16* __restrict__ Bt,
    const float* __restrict__ bias, float* __restrict__ outp)
{
    __shared__ __align__(16) bf16 As[2][128 * 32];
    __shared__ __align__(16) bf16 Bs[2][256 * 32];

    const int t    = threadIdx.x;
    const int lane = t & 63;
    const int wv   = t >> 6;
    const int wr   = wv >> 2;
    const int wc   = wv & 3;
    const int g    = lane >> 4, r16 = lane & 15;

    const int nwg = gridDim.x;
    const int bid = blockIdx.x;
    const int swz = (bid & 7) * (nwg >> 3) + (bid >> 3);
    const int m0  = (swz / NT) * 128;
    const int n0  = (swz % NT) * 256;

    const int L0 = wv * 64 + lane;
    const int rA = L0 >> 2,          sA = ((L0 & 3) - (rA >> 1)) & 3;
    const int rB1 = rA + 128,        sB1v = ((L0 & 3) - (rB1 >> 1)) & 3;
    const bf16* srcA  = Ag + (size_t)(m0 + rA) * CDIM + sA * 8;
    const bf16* srcB0 = Bt + (size_t)(n0 + rA) * CDIM + sA * 8;
    const bf16* srcB1 = Bt + (size_t)(n0 + rB1) * CDIM + sB1v * 8;

    int aoff[4], boff[4];
#pragma unroll
    for (int m = 0; m < 4; ++m) {
        int row = wr * 64 + m * 16 + r16;
        aoff[m] = row * 64 + (((g + (row >> 1)) & 3) << 4);
    }
#pragma unroll
    for (int n = 0; n < 4; ++n) {
        int row = wc * 64 + n * 16 + r16;
        boff[n] = row * 64 + (((g + (row >> 1)) & 3) << 4);
    }

    f32x4 acc[4][4];
    const f32x4 z = {0.f, 0.f, 0.f, 0.f};
#pragma unroll
    for (int m = 0; m < 4; ++m)
#pragma unroll
        for (int n = 0; n < 4; ++n) acc[m][n] = z;

    auto stage = [&](int kt) {
        const int b  = kt & 1;
        const int ko = kt * 32;
        gld16(srcA  + ko, &As[b][(size_t)wv * 64 * 8]);
        gld16(srcB0 + ko, &Bs[b][(size_t)wv * 64 * 8]);
        gld16(srcB1 + ko, &Bs[b][(size_t)(512 + wv * 64) * 8]);
    };

    auto compute = [&](int kt) {
        const int b = kt & 1;
        bf16x8 af[4], bvv[4];
#pragma unroll
        for (int m = 0; m < 4; ++m)
            af[m] = *reinterpret_cast<const bf16x8*>(
                reinterpret_cast<const char*>(&As[b][0]) + aoff[m]);
#pragma unroll
        for (int n = 0; n < 4; ++n)
            bvv[n] = *reinterpret_cast<const bf16x8*>(
                reinterpret_cast<const char*>(&Bs[b][0]) + boff[n]);
        __builtin_amdgcn_s_setprio(1);
#pragma unroll
        for (int m = 0; m < 4; ++m)
#pragma unroll
            for (int n = 0; n < 4; ++n)
                acc[m][n] = __builtin_amdgcn_mfma_f32_16x16x32_bf16(
                    af[m], bvv[n], acc[m][n], 0, 0, 0);
        __builtin_amdgcn_s_setprio(0);
    };

    const int NKT = CDIM / 32;

    stage(0); stage(1);
    asm volatile("s_waitcnt vmcnt(3)" ::: "memory");
    __builtin_amdgcn_s_barrier();

#pragma unroll
    for (int kt = 0; kt < NKT - 2; ++kt) {
        compute(kt);
        asm volatile("s_waitcnt lgkmcnt(0)" ::: "memory");
        __builtin_amdgcn_s_barrier();
        stage(kt + 2);
        asm volatile("s_waitcnt vmcnt(3)" ::: "memory");
        __builtin_amdgcn_s_barrier();
    }
    compute(NKT - 2);
    asm volatile("s_waitcnt vmcnt(0) lgkmcnt(0)" ::: "memory");
    __builtin_amdgcn_s_barrier();
    compute(NKT - 1);

    const int ldo = NT * 256;
#pragma unroll
    for (int n = 0; n < 4; ++n) {
        int col = n0 + wc * 64 + n * 16 + r16;
        float b = bias[col];
#pragma unroll
        for (int m = 0; m < 4; ++m)
#pragma unroll
            for (int j = 0; j < 4; ++j) {
                int row = m0 + wr * 64 + m * 16 + g * 4 + j;
                outp[(size_t)row * ldo + col] = acc[m][n][j] + b;
            }
    }
}

// ---------------------------------------------------------------------------
// Attention: one block per (window, head). 4 waves, each owns 32 query rows.
// V-transpose now uses per-lane ROTATED stores (rot128): for wave-inst k the
// 8 lanes of a tok-group write rows c8+((k+rot)&7) -> banks 4*((k+rot)&7)
// all distinct (was 8-way same-bank). Reads unchanged (2-way, free).
// Output rows SCATTERED to attn_g[order[w*128+tok]].
// ---------------------------------------------------------------------------
__global__ __launch_bounds__(256, 2) void k_attn(
    const bf16* __restrict__ qkv_s, const int* __restrict__ order,
    bf16* __restrict__ attn_g)
{
    __shared__ __align__(16) char smem[36864 + 64 * 136 * 2];
    __shared__ int ord_s[KWIN];
    bf16 (*Q)[72]   = reinterpret_cast<bf16 (*)[72]>(smem);
    bf16 (*Kt)[72]  = reinterpret_cast<bf16 (*)[72]>(smem + 128 * 72 * 2);
    bf16 (*P)[136]  = reinterpret_cast<bf16 (*)[136]>(smem);          // overlaps Q,Kt
    bf16 (*Vt)[136] = reinterpret_cast<bf16 (*)[136]>(smem + 36864);  // V transposed
    unsigned short* Vtu = reinterpret_cast<unsigned short*>(smem + 36864);

    const int t    = threadIdx.x;
    const int lane = t & 63;
    const int wv   = t >> 6;
    const int g    = lane >> 4, r16 = lane & 15;
    const int h    = blockIdx.x;
    const int w    = blockIdx.y;

    const bf16* base = qkv_s + (size_t)w * KWIN * C3 + h * HD;

    if (t < KWIN) ord_s[t] = order[w * KWIN + t];

    const int rot = t & 7;

    // stage Q, K (row-major [tok][d]) and V transposed [d][tok] (rotated)
#pragma unroll
    for (int it = 0; it < 4; ++it) {
        int s   = it * 256 + t;      // 0..1023
        int tok = s >> 3;
        int c8  = (s & 7) << 3;
        size_t roff = (size_t)tok * C3 + c8;
        *reinterpret_cast<uint4*>(&Q[tok][c8])  =
            *reinterpret_cast<const uint4*>(base + roff);
        *reinterpret_cast<uint4*>(&Kt[tok][c8]) =
            *reinterpret_cast<const uint4*>(base + roff + CDIM);
        uint4 vvec = *reinterpret_cast<const uint4*>(base + roff + 2 * CDIM);
        uint4 vr = rot128(vvec, rot);
        uint32_t wd[4] = {vr.x, vr.y, vr.z, vr.w};
#pragma unroll
        for (int k = 0; k < 8; ++k) {
            int d = c8 + ((k + rot) & 7);
            Vtu[d * 136 + tok] =
                (unsigned short)(wd[k >> 1] >> ((k & 1) * 16));
        }
    }
    __syncthreads();

    // S = Q K^T for rows [wv*32, wv*32+32)
    f32x4 sc[2][8];
    const f32x4 z = {0.f, 0.f, 0.f, 0.f};
#pragma unroll
    for (int m = 0; m < 2; ++m)
#pragma unroll
        for (int n = 0; n < 8; ++n) sc[m][n] = z;

#pragma unroll
    for (int ks = 0; ks < 2; ++ks) {
        bf16x8 aq[2];
#pragma unroll
        for (int m = 0; m < 2; ++m)
            aq[m] = *reinterpret_cast<const bf16x8*>(
                &Q[wv * 32 + m * 16 + r16][ks * 32 + g * 8]);
#pragma unroll
        for (int n = 0; n < 8; ++n) {
            bf16x8 bk = *reinterpret_cast<const bf16x8*>(
                &Kt[n * 16 + r16][ks * 32 + g * 8]);
#pragma unroll
            for (int m = 0; m < 2; ++m)
                sc[m][n] = __builtin_amdgcn_mfma_f32_16x16x32_bf16(
                    aq[m], bk, sc[m][n], 0, 0, 0);
        }
    }

    // softmax (f32), row-parallel over 16-lane groups
    const float scale = 0.125f;   // hd^-0.5
    float inv_sum[2][4];
#pragma unroll
    for (int m = 0; m < 2; ++m) {
#pragma unroll
        for (int j = 0; j < 4; ++j) {
            float mx = -3.0e38f;
#pragma unroll
            for (int n = 0; n < 8; ++n) mx = fmaxf(mx, sc[m][n][j]);
            mx = fmaxf(mx, __shfl_xor(mx, 1));
            mx = fmaxf(mx, __shfl_xor(mx, 2));
            mx = fmaxf(mx, __shfl_xor(mx, 4));
            mx = fmaxf(mx, __shfl_xor(mx, 8));
            mx *= scale;
            float ssum = 0.f;
#pragma unroll
            for (int n = 0; n < 8; ++n) {
                float p = __expf(sc[m][n][j] * scale - mx);
                sc[m][n][j] = p;
                ssum += p;
            }
            ssum += __shfl_xor(ssum, 1);
            ssum += __shfl_xor(ssum, 2);
            ssum += __shfl_xor(ssum, 4);
            ssum += __shfl_xor(ssum, 8);
            inv_sum[m][j] = 1.f / ssum;
        }
    }

    __syncthreads();   // all waves done reading Q/Kt before P overwrites them

    // write normalized P (bf16)
#pragma unroll
    for (int m = 0; m < 2; ++m)
#pragma unroll
        for (int n = 0; n < 8; ++n)
#pragma unroll
            for (int j = 0; j < 4; ++j)
                P[wv * 32 + m * 16 + g * 4 + j][n * 16 + r16] =
                    cvt(sc[m][n][j] * inv_sum[m][j]);

    // O = P V   (32x64 per wave)
    f32x4 o[2][4];
#pragma unroll
    for (int m = 0; m < 2; ++m)
#pragma unroll
        for (int n = 0; n < 4; ++n) o[m][n] = z;

#pragma unroll
    for (int kt = 0; kt < 4; ++kt) {
        bf16x8 ap[2];
#pragma unroll
        for (int m = 0; m < 2; ++m)
            ap[m] = *reinterpret_cast<const bf16x8*>(
                &P[wv * 32 + m * 16 + r16][kt * 32 + g * 8]);
#pragma unroll
        for (int n = 0; n < 4; ++n) {
            bf16x8 bvv = *reinterpret_cast<const bf16x8*>(
                &Vt[n * 16 + r16][kt * 32 + g * 8]);
#pragma unroll
            for (int m = 0; m < 2; ++m)
                o[m][n] = __builtin_amdgcn_mfma_f32_16x16x32_bf16(
                    ap[m], bvv, o[m][n], 0, 0, 0);
        }
    }

    // scatter rows to unserialized position: attn_g[order[i]] = ser[i]
#pragma unroll
    for (int m = 0; m < 2; ++m)
#pragma unroll
        for (int n = 0; n < 4; ++n)
#pragma unroll
            for (int j = 0; j < 4; ++j) {
                int tok  = wv * 32 + m * 16 + g * 4 + j;
                int d    = n * 16 + r16;
                int drow = ord_s[tok];
                attn_g[(size_t)drow * CDIM + h * HD + d] = cvt(o[m][n][j]);
            }
}

// ---------------------------------------------------------------------------
extern "C" void kernel_launch(void* const* d_in, const int* in_sizes, int n_in,
                              void* d_out, int out_size, void* d_ws, size_t ws_size,
                              hipStream_t stream)
{
    const float* feat    = (const float*)d_in[0];
    const float* Wqkv    = (const float*)d_in[1];
    const float* bqkv    = (const float*)d_in[2];
    const float* Wproj   = (const float*)d_in[3];
    const float* bproj   = (const float*)d_in[4];
    const int*   order   = (const int*)d_in[5];
    float* out = (float*)d_out;

    const size_t qkv_bytes  = (size_t)N_PTS * C3 * sizeof(bf16);    // 402.7 MB
    const size_t gat_bytes  = (size_t)N_PTS * CDIM * sizeof(bf16);  // 134.2 MB (attn_g)
    const size_t wq_bytes   = (size_t)C3 * CDIM * sizeof(bf16);
    const size_t wp_bytes   = (size_t)CDIM * CDIM * sizeof(bf16);
    if (ws_size < qkv_bytes + gat_bytes + wq_bytes + wp_bytes) return;

    bf16* qkv_s   = (bf16*)d_ws;
    bf16* attn_g  = (bf16*)((char*)d_ws + qkv_bytes);
    bf16* Wqkv_t  = (bf16*)((char*)d_ws + qkv_bytes + gat_bytes);
    bf16* Wproj_t = (bf16*)((char*)d_ws + qkv_bytes + gat_bytes + wq_bytes);

    k_prep<<<dim3((CDIM * C3 + CDIM * CDIM + 255) / 256), 256, 0, stream>>>(
        Wqkv, Wproj, Wqkv_t, Wproj_t);
    // qkv GEMM with fused gather: [131072 x 1536] = bf16(feat[order]) @ Wqkv_t^T
    k_qkv4<C3 / 256>
        <<<dim3((N_PTS / 128) * (C3 / 256)), 256, 0, stream>>>(
        feat, Wqkv_t, bqkv, order, qkv_s);
    // attention (reads qkv_s, scatters into attn_g)
    k_attn<<<dim3(NH, N_PTS / KWIN), 256, 0, stream>>>(qkv_s, order, attn_g);
    // proj GEMM: [131072 x 512] = attn_g @ Wproj_t^T  (f32 out)
    k_proj<CDIM / 256>
        <<<dim3((N_PTS / 128) * (CDIM / 256)), 512, 0, stream>>>(
        attn_g, Wproj_t, bproj, out);
}